// Round 2
// baseline (467.101 us; speedup 1.0000x reference)
//
#include <hip/hip_runtime.h>

typedef __bf16 bf16_t;
typedef __bf16 bf16x8 __attribute__((ext_vector_type(8)));
typedef float floatx4 __attribute__((ext_vector_type(4)));

#define MFMA16(a, b, c) __builtin_amdgcn_mfma_f32_16x16x32_bf16(a, b, c, 0, 0, 0)

struct TPtrs { const void* src[5]; bf16_t* dst[5]; };
struct GPtrs { const bf16_t* Bt[4]; bf16_t* C[4]; };

// ---------------------------------------------------------------------------
// Detect input dtype on-device. Reinterpret low 16 bits of Wq words as bf16:
// bf16-world -> genuine weights (~100% in [1e-5,4]); fp32-world -> mantissa
// noise (~8% plausible). flag=1 means bf16 inputs.
// ---------------------------------------------------------------------------
__global__ __launch_bounds__(256) void detect_dtype_kernel(const unsigned int* W,
                                                           int* flag) {
    int tid = threadIdx.x;
    int cnt = 0;
    for (int i = tid; i < 4096; i += 256) {
        unsigned int fb = (W[i] & 0xFFFFu) << 16;
        float v = __uint_as_float(fb);
        float a = fabsf(v);
        if (a > 1e-5f && a < 4.f) cnt++;
    }
    __shared__ int s[256];
    s[tid] = cnt;
    __syncthreads();
    for (int st = 128; st > 0; st >>= 1) {
        if (tid < st) s[tid] += s[tid + st];
        __syncthreads();
    }
    if (tid == 0) *flag = (s[0] > 2048) ? 1 : 0;
}

// ---------------------------------------------------------------------------
// Canonicalize x -> bf16. 8,388,608 elems, 8/thread, grid 4096.
// ---------------------------------------------------------------------------
__global__ __launch_bounds__(256) void convert_x_kernel(const void* __restrict__ src,
                                                        bf16_t* __restrict__ dst,
                                                        const int* __restrict__ flag) {
    size_t i0 = ((size_t)blockIdx.x * 256 + threadIdx.x) * 8;
    bf16x8 o;
    if (*flag) {
        o = *(const bf16x8*)((const bf16_t*)src + i0);
    } else {
        const float* s = (const float*)src + i0;
        float4 a = *(const float4*)s;
        float4 b = *(const float4*)(s + 4);
        o[0] = (bf16_t)a.x; o[1] = (bf16_t)a.y; o[2] = (bf16_t)a.z; o[3] = (bf16_t)a.w;
        o[4] = (bf16_t)b.x; o[5] = (bf16_t)b.y; o[6] = (bf16_t)b.z; o[7] = (bf16_t)b.w;
    }
    *(bf16x8*)(dst + i0) = o;
}

// ---------------------------------------------------------------------------
// Transpose 2048x2048 -> bf16: dst[n][k] = (bf16)src[k][n]. grid (32,32,5).
// ---------------------------------------------------------------------------
__global__ __launch_bounds__(256) void transpose_k(TPtrs p, const int* __restrict__ flag) {
    __shared__ bf16_t tile[64][72];  // +8 pad
    int z = blockIdx.z;
    bf16_t* dst = p.dst[z];
    int bx = blockIdx.x, by = blockIdx.y;
    int tid = threadIdx.x;
    int isbf = *flag;
#pragma unroll
    for (int l = 0; l < 2; ++l) {
        int idx = tid + 256 * l;          // 512 x 8 elems = 64 rows x 64 cols
        int r = idx >> 3, c8 = (idx & 7) * 8;
        bf16x8 o;
        if (isbf) {
            const bf16_t* src = (const bf16_t*)p.src[z];
            o = *(const bf16x8*)&src[(size_t)(by * 64 + r) * 2048 + bx * 64 + c8];
        } else {
            const float* src = (const float*)p.src[z];
            const float* sp = &src[(size_t)(by * 64 + r) * 2048 + bx * 64 + c8];
            float4 a = *(const float4*)sp;
            float4 b = *(const float4*)(sp + 4);
            o[0] = (bf16_t)a.x; o[1] = (bf16_t)a.y; o[2] = (bf16_t)a.z; o[3] = (bf16_t)a.w;
            o[4] = (bf16_t)b.x; o[5] = (bf16_t)b.y; o[6] = (bf16_t)b.z; o[7] = (bf16_t)b.w;
        }
        *(bf16x8*)&tile[r][c8] = o;
    }
    __syncthreads();
#pragma unroll
    for (int l = 0; l < 2; ++l) {
        int idx = tid + 256 * l;
        int r = idx >> 3, c8 = (idx & 7) * 8;
        bf16x8 o;
#pragma unroll
        for (int m = 0; m < 8; ++m) o[m] = tile[c8 + m][r];
        *(bf16x8*)&dst[(size_t)(bx * 64 + r) * 2048 + by * 64 + c8] = o;
    }
}

// ---------------------------------------------------------------------------
// GEMM  C[M,N] = A[M,K] @ Bt[N,K]^T, bf16 out.  BM=BN=128, BK=64, 4 waves.
// blockIdx.z selects Bt/C pair (QKVG fused launch).
// ---------------------------------------------------------------------------
__global__ __launch_bounds__(256) void gemm_bt(const bf16_t* __restrict__ A, GPtrs p,
                                               int K) {
    constexpr int BM = 128, BK = 64, LDP = BK + 8;
    __shared__ bf16_t sA[BM][LDP];
    __shared__ bf16_t sB[BM][LDP];
    const bf16_t* __restrict__ Bt = p.Bt[blockIdx.z];
    bf16_t* __restrict__ C = p.C[blockIdx.z];
    const int N = 2048;
    int tid = threadIdx.x, lane = tid & 63, wid = tid >> 6;
    int l15 = lane & 15, quad = lane >> 4;
    int wm = wid >> 1, wn = wid & 1;
    int m0 = blockIdx.y * BM, n0 = blockIdx.x * BM;

    floatx4 acc[4][4] = {};
    for (int kk = 0; kk < K; kk += BK) {
#pragma unroll
        for (int l = 0; l < 4; ++l) {
            int idx = tid + 256 * l;      // 1024 x 8 elems = 128 rows x 64
            int row = idx >> 3, c8 = (idx & 7) * 8;
            *(bf16x8*)&sA[row][c8] = *(const bf16x8*)&A[(size_t)(m0 + row) * K + kk + c8];
            *(bf16x8*)&sB[row][c8] = *(const bf16x8*)&Bt[(size_t)(n0 + row) * K + kk + c8];
        }
        __syncthreads();
#pragma unroll
        for (int k2 = 0; k2 < 2; ++k2) {
            int koff = k2 * 32 + quad * 8;
            bf16x8 af[4], bfv[4];
#pragma unroll
            for (int i = 0; i < 4; ++i)
                af[i] = *(const bf16x8*)&sA[wm * 64 + i * 16 + l15][koff];
#pragma unroll
            for (int j = 0; j < 4; ++j)
                bfv[j] = *(const bf16x8*)&sB[wn * 64 + j * 16 + l15][koff];
#pragma unroll
            for (int i = 0; i < 4; ++i)
#pragma unroll
                for (int j = 0; j < 4; ++j)
                    acc[i][j] = MFMA16(af[i], bfv[j], acc[i][j]);
        }
        __syncthreads();
    }
#pragma unroll
    for (int i = 0; i < 4; ++i)
#pragma unroll
        for (int j = 0; j < 4; ++j)
#pragma unroll
            for (int r = 0; r < 4; ++r) {
                int row = m0 + wm * 64 + i * 16 + quad * 4 + r;
                int col = n0 + wn * 64 + j * 16 + l15;
                C[(size_t)row * N + col] = (bf16_t)acc[i][j][r];
            }
}

// ---------------------------------------------------------------------------
// Final GEMM: out dtype dynamic (flag=1 -> bf16, else fp32).
// ---------------------------------------------------------------------------
__global__ __launch_bounds__(256) void gemm_bt_dyn(const bf16_t* __restrict__ A,
                                                   const bf16_t* __restrict__ Bt,
                                                   void* __restrict__ C, int K,
                                                   const int* __restrict__ flag) {
    constexpr int BM = 128, BK = 64, LDP = BK + 8;
    __shared__ bf16_t sA[BM][LDP];
    __shared__ bf16_t sB[BM][LDP];
    const int N = 2048;
    int tid = threadIdx.x, lane = tid & 63, wid = tid >> 6;
    int l15 = lane & 15, quad = lane >> 4;
    int wm = wid >> 1, wn = wid & 1;
    int m0 = blockIdx.y * BM, n0 = blockIdx.x * BM;
    int isbf = *flag;

    floatx4 acc[4][4] = {};
    for (int kk = 0; kk < K; kk += BK) {
#pragma unroll
        for (int l = 0; l < 4; ++l) {
            int idx = tid + 256 * l;
            int row = idx >> 3, c8 = (idx & 7) * 8;
            *(bf16x8*)&sA[row][c8] = *(const bf16x8*)&A[(size_t)(m0 + row) * K + kk + c8];
            *(bf16x8*)&sB[row][c8] = *(const bf16x8*)&Bt[(size_t)(n0 + row) * K + kk + c8];
        }
        __syncthreads();
#pragma unroll
        for (int k2 = 0; k2 < 2; ++k2) {
            int koff = k2 * 32 + quad * 8;
            bf16x8 af[4], bfv[4];
#pragma unroll
            for (int i = 0; i < 4; ++i)
                af[i] = *(const bf16x8*)&sA[wm * 64 + i * 16 + l15][koff];
#pragma unroll
            for (int j = 0; j < 4; ++j)
                bfv[j] = *(const bf16x8*)&sB[wn * 64 + j * 16 + l15][koff];
#pragma unroll
            for (int i = 0; i < 4; ++i)
#pragma unroll
                for (int j = 0; j < 4; ++j)
                    acc[i][j] = MFMA16(af[i], bfv[j], acc[i][j]);
        }
        __syncthreads();
    }
#pragma unroll
    for (int i = 0; i < 4; ++i)
#pragma unroll
        for (int j = 0; j < 4; ++j)
#pragma unroll
            for (int r = 0; r < 4; ++r) {
                int row = m0 + wm * 64 + i * 16 + quad * 4 + r;
                int col = n0 + wn * 64 + j * 16 + l15;
                if (isbf) ((bf16_t*)C)[(size_t)row * N + col] = (bf16_t)acc[i][j][r];
                else      ((float*)C)[(size_t)row * N + col] = acc[i][j][r];
            }
}

// ---------------------------------------------------------------------------
// RoPE (rotate-half, base 10000) in place on [B,S,H,128]; q also scaled.
// ---------------------------------------------------------------------------
__global__ __launch_bounds__(256) void rope_kernel(bf16_t* X, float scale) {
    size_t gt = (size_t)blockIdx.x * 256 + threadIdx.x;
    int i = gt & 63;
    int h = (gt >> 6) & 15;
    int s = (gt >> 10) & 2047;
    int b = gt >> 21;
    size_t base = ((size_t)((b * 2048 + s) * 16 + h)) << 7;
    float inv = exp2f(-(float)i * (13.287712379549449f / 64.f));  // 10000^(-i/64)
    float ang = (float)s * inv;
    float sn, cs;
    sincosf(ang, &sn, &cs);
    float x1 = (float)X[base + i];
    float x2 = (float)X[base + 64 + i];
    X[base + i]      = (bf16_t)((x1 * cs - x2 * sn) * scale);
    X[base + 64 + i] = (bf16_t)((x2 * cs + x1 * sn) * scale);
}

// ---------------------------------------------------------------------------
// Pass A: Ut[e][d] = sum_t v[t][e] * gamma^(63-t) * k[t][d].  grid 1024.
// ---------------------------------------------------------------------------
__global__ __launch_bounds__(256) void chunk_state_kernel(const bf16_t* __restrict__ Kc,
                                                          const bf16_t* __restrict__ Vc,
                                                          bf16_t* __restrict__ U) {
    __shared__ bf16_t sKT[128][72];
    __shared__ bf16_t sVT[128][72];
    int bx = blockIdx.x;
    int n = bx & 31, h = (bx >> 5) & 15, b = bx >> 9;
    int tid = threadIdx.x, lane = tid & 63, wid = tid >> 6;
    int l15 = lane & 15, quad = lane >> 4;
    int wm = wid >> 1, wn = wid & 1;
    float log2g = log2f(1.f - exp2f(-5.f - (float)h));

#pragma unroll
    for (int l = 0; l < 4; ++l) {
        int idx = tid + 256 * l;          // 1024 = 64 rows x 16 vec8
        int t = idx >> 4, d8 = (idx & 15) * 8;
        size_t gb = (((size_t)((b * 2048 + n * 64 + t) * 16 + h)) << 7) + d8;
        bf16x8 kv = *(const bf16x8*)&Kc[gb];
        bf16x8 vv = *(const bf16x8*)&Vc[gb];
        float kdec = exp2f((float)(63 - t) * log2g);
#pragma unroll
        for (int m = 0; m < 8; ++m) {
            sKT[d8 + m][t] = (bf16_t)((float)kv[m] * kdec);
            sVT[d8 + m][t] = vv[m];
        }
    }
    __syncthreads();

    floatx4 acc[4][4] = {};
#pragma unroll
    for (int k2 = 0; k2 < 2; ++k2) {
        int t0 = k2 * 32 + quad * 8;
        bf16x8 af[4], bfv[4];
#pragma unroll
        for (int i = 0; i < 4; ++i) af[i] = *(const bf16x8*)&sVT[wm * 64 + i * 16 + l15][t0];
#pragma unroll
        for (int j = 0; j < 4; ++j) bfv[j] = *(const bf16x8*)&sKT[wn * 64 + j * 16 + l15][t0];
#pragma unroll
        for (int i = 0; i < 4; ++i)
#pragma unroll
            for (int j = 0; j < 4; ++j) acc[i][j] = MFMA16(af[i], bfv[j], acc[i][j]);
    }
    size_t ub = (size_t)bx * 16384;
#pragma unroll
    for (int i = 0; i < 4; ++i)
#pragma unroll
        for (int j = 0; j < 4; ++j)
#pragma unroll
            for (int r = 0; r < 4; ++r) {
                int e = wm * 64 + i * 16 + quad * 4 + r;
                int d = wn * 64 + j * 16 + l15;
                U[ub + (size_t)e * 128 + d] = (bf16_t)acc[i][j][r];
            }
}

// ---------------------------------------------------------------------------
// Pass B: in-place scan  St[n] = state before chunk n (transposed layout).
// ---------------------------------------------------------------------------
__global__ __launch_bounds__(256) void scan_kernel(bf16_t* __restrict__ US) {
    int bx = blockIdx.x;
    int bh = bx >> 3, slice = bx & 7;
    int h = bh & 15;
    float log2g = log2f(1.f - exp2f(-5.f - (float)h));
    float gC = exp2f(64.f * log2g);
    size_t base = (size_t)bh * 32 * 16384 + (size_t)slice * 2048 + (size_t)threadIdx.x * 8;
    float acc[8] = {};
    for (int n = 0; n < 32; ++n) {
        size_t o = base + (size_t)n * 16384;
        bf16x8 u = *(const bf16x8*)&US[o];
        bf16x8 s;
#pragma unroll
        for (int m = 0; m < 8; ++m) s[m] = (bf16_t)acc[m];
        *(bf16x8*)&US[o] = s;
#pragma unroll
        for (int m = 0; m < 8; ++m) acc[m] = gC * acc[m] + (float)u[m];
    }
}

// ---------------------------------------------------------------------------
// Pass C: chunk output + gated RMSNorm.  grid 1024.
// ---------------------------------------------------------------------------
__global__ __launch_bounds__(256) void chunk_out_kernel(
    const bf16_t* __restrict__ Q, const bf16_t* __restrict__ Kc,
    const bf16_t* __restrict__ Vc, const bf16_t* __restrict__ G,
    const void* __restrict__ gwp, const bf16_t* __restrict__ St,
    bf16_t* __restrict__ OG, const int* __restrict__ flag) {
    __shared__ bf16_t sQ[64][136];
    __shared__ bf16_t sK[64][136];
    __shared__ bf16_t sVT[128][72];
    __shared__ bf16_t sA[64][72];
    __shared__ float sgw[128];
    int bx = blockIdx.x;
    int n = bx & 31, h = (bx >> 5) & 15, b = bx >> 9;
    int tid = threadIdx.x, lane = tid & 63, wid = tid >> 6;
    int l15 = lane & 15, quad = lane >> 4;
    float log2g = log2f(1.f - exp2f(-5.f - (float)h));

    if (tid < 128) {
        sgw[tid] = (*flag) ? (float)((const bf16_t*)gwp)[tid] : ((const float*)gwp)[tid];
    }
#pragma unroll
    for (int l = 0; l < 4; ++l) {
        int idx = tid + 256 * l;
        int t = idx >> 4, d8 = (idx & 15) * 8;
        size_t gb = (((size_t)((b * 2048 + n * 64 + t) * 16 + h)) << 7) + d8;
        *(bf16x8*)&sQ[t][d8] = *(const bf16x8*)&Q[gb];
        *(bf16x8*)&sK[t][d8] = *(const bf16x8*)&Kc[gb];
        bf16x8 vv = *(const bf16x8*)&Vc[gb];
#pragma unroll
        for (int m = 0; m < 8; ++m) sVT[d8 + m][t] = vv[m];
    }
    __syncthreads();

    // ---- phase 1: A = q k^T (64x64), decay mask, stash bf16 in sA
    int t0 = wid * 16;
    floatx4 accA[4] = {};
#pragma unroll
    for (int kk = 0; kk < 4; ++kk) {
        int d0 = kk * 32 + quad * 8;
        bf16x8 aq = *(const bf16x8*)&sQ[t0 + l15][d0];
#pragma unroll
        for (int j = 0; j < 4; ++j) {
            bf16x8 bk = *(const bf16x8*)&sK[j * 16 + l15][d0];
            accA[j] = MFMA16(aq, bk, accA[j]);
        }
    }
#pragma unroll
    for (int j = 0; j < 4; ++j)
#pragma unroll
        for (int r = 0; r < 4; ++r) {
            int t = t0 + quad * 4 + r;
            int s = j * 16 + l15;
            int rel = t - s;
            float v = (rel >= 0) ? accA[j][r] * exp2f((float)rel * log2g) : 0.f;
            sA[t][s] = (bf16_t)v;
        }
    __syncthreads();

    // ---- phase 2: o = A v + (q*cross) S
    floatx4 acc[8] = {};
#pragma unroll
    for (int kk = 0; kk < 2; ++kk) {          // K = 64 (s)
        int s0 = kk * 32 + quad * 8;
        bf16x8 aa = *(const bf16x8*)&sA[t0 + l15][s0];
#pragma unroll
        for (int j = 0; j < 8; ++j) {
            bf16x8 bv = *(const bf16x8*)&sVT[j * 16 + l15][s0];
            acc[j] = MFMA16(aa, bv, acc[j]);
        }
    }
    size_t sb = (size_t)bx * 16384;
    float crossf = exp2f((float)(t0 + l15 + 1) * log2g);
#pragma unroll
    for (int kk = 0; kk < 4; ++kk) {          // K = 128 (d)
        int d0 = kk * 32 + quad * 8;
        bf16x8 aq = *(const bf16x8*)&sQ[t0 + l15][d0];
        bf16x8 aqs;
#pragma unroll
        for (int m = 0; m < 8; ++m) aqs[m] = (bf16_t)((float)aq[m] * crossf);
#pragma unroll
        for (int j = 0; j < 8; ++j) {
            bf16x8 bs = *(const bf16x8*)&St[sb + (size_t)(j * 16 + l15) * 128 + d0];
            acc[j] = MFMA16(aqs, bs, acc[j]);
        }
    }

    // ---- epilogue: gated RMSNorm per row t
#pragma unroll
    for (int r = 0; r < 4; ++r) {
        float ss = 0.f;
#pragma unroll
        for (int j = 0; j < 8; ++j) ss += acc[j][r] * acc[j][r];
        ss += __shfl_xor(ss, 1);
        ss += __shfl_xor(ss, 2);
        ss += __shfl_xor(ss, 4);
        ss += __shfl_xor(ss, 8);
        float rms = rsqrtf(ss * (1.f / 128.f) + 1e-5f);
        int t = t0 + quad * 4 + r;
        size_t gb = ((size_t)((b * 2048 + n * 64 + t) * 16 + h)) << 7;
#pragma unroll
        for (int j = 0; j < 8; ++j) {
            int e = j * 16 + l15;
            float g_ = (float)G[gb + e];
            float sw = g_ / (1.f + expf(-g_));
            OG[gb + e] = (bf16_t)(acc[j][r] * rms * sgw[e] * sw);
        }
    }
}

// ---------------------------------------------------------------------------
extern "C" void kernel_launch(void* const* d_in, const int* in_sizes, int n_in,
                              void* d_out, int out_size, void* d_ws, size_t ws_size,
                              hipStream_t stream) {
    char* ws = (char*)d_ws;
    const size_t WBYTES = 2048ull * 2048 * 2;   // 8 MiB per bf16 weight
    const size_t ABYTES = 4096ull * 2048 * 2;   // 16 MiB per bf16 activation
    int* flag = (int*)ws;
    char* base = ws + 256;
    bf16_t* xb = (bf16_t*)base;
    bf16_t* WT[5];
    for (int i = 0; i < 5; ++i) WT[i] = (bf16_t*)(base + ABYTES + i * WBYTES);
    char* act = base + ABYTES + 5 * WBYTES;
    bf16_t* qb = (bf16_t*)(act + 0 * ABYTES);
    bf16_t* kb = (bf16_t*)(act + 1 * ABYTES);
    bf16_t* vb = (bf16_t*)(act + 2 * ABYTES);
    bf16_t* gb = (bf16_t*)(act + 3 * ABYTES);
    bf16_t* og = (bf16_t*)(act + 4 * ABYTES);
    bf16_t* US = (bf16_t*)(act + 5 * ABYTES);  // 32 MiB

    // 0. detect dtype (flag=1 -> bf16 inputs)
    detect_dtype_kernel<<<1, 256, 0, stream>>>((const unsigned int*)d_in[1], flag);

    // 1. canonicalize x; transpose+canonicalize all 5 weights
    convert_x_kernel<<<4096, 256, 0, stream>>>(d_in[0], xb, flag);
    TPtrs tp;
    tp.src[0] = d_in[1]; tp.src[1] = d_in[2]; tp.src[2] = d_in[3];
    tp.src[3] = d_in[4]; tp.src[4] = d_in[6];
    for (int i = 0; i < 5; ++i) tp.dst[i] = WT[i];
    transpose_k<<<dim3(32, 32, 5), 256, 0, stream>>>(tp, flag);

    // 2. fused QKVG projections
    GPtrs gp;
    gp.Bt[0] = WT[0]; gp.Bt[1] = WT[1]; gp.Bt[2] = WT[2]; gp.Bt[3] = WT[3];
    gp.C[0] = qb; gp.C[1] = kb; gp.C[2] = vb; gp.C[3] = gb;
    gemm_bt<<<dim3(16, 32, 4), 256, 0, stream>>>(xb, gp, 2048);

    // 3. RoPE (q scaled by DK^-0.5)
    rope_kernel<<<16384, 256, 0, stream>>>(qb, 0.08838834764831845f);
    rope_kernel<<<16384, 256, 0, stream>>>(kb, 1.0f);

    // 4. retention
    chunk_state_kernel<<<1024, 256, 0, stream>>>(kb, vb, US);
    scan_kernel<<<256, 256, 0, stream>>>(US);
    chunk_out_kernel<<<1024, 256, 0, stream>>>(qb, kb, vb, gb, d_in[5], US, og, flag);

    // 5. output projection (dtype-dynamic store)
    gemm_bt_dyn<<<dim3(16, 32, 1), 256, 0, stream>>>(og, WT[4], d_out, 2048, flag);
}